// Round 1
// 860.048 us; speedup vs baseline: 1.0330x; 1.0330x over previous
//
#include <hip/hip_runtime.h>

#define NB 2
#define NH 16
#define SS 2048
#define DM 1024
#define DK 64
#define MM 4096  // NB*SS

typedef __attribute__((ext_vector_type(8))) short short8;
typedef __attribute__((ext_vector_type(4))) float floatx4;
typedef unsigned short u16;
typedef unsigned int u32;

// ws layout (bytes)
#define WS_X    0            // 3 x [4096][1024] bf16 (q,k,v casts), 8MB each
#define WS_WT   25165824     // 4 x [1024][1024] bf16 transposed W, 2MB each
#define WS_QH   33554432     // [B,H,S,DK] bf16 (pre-scaled by 1/8)
#define WS_KH   41943040     // [B,H,S,DK] bf16
#define WS_VH   50331648     // [B,H,S,DK] bf16
#define WS_VT   58720256     // [B,H,DK,S] bf16
#define WS_CTX  67108864     // [4096][1024] bf16

__device__ inline u16 f2bf(float f) {
    union { float f; u32 u; } x; x.f = f;
    u32 u = x.u;
    return (u16)((u + 0x7fffu + ((u >> 16) & 1u)) >> 16);
}

// ---------- cast+transpose the four weight matrices to bf16 Wt[n][k] ----------
__global__ __launch_bounds__(256) void wcast_kernel(
    const float* __restrict__ Wq, const float* __restrict__ Wk,
    const float* __restrict__ Wv, const float* __restrict__ Wo,
    u16* __restrict__ wt)
{
    __shared__ float tile[32][33];
    int mat = blockIdx.z;
    const float* W = (mat == 0) ? Wq : (mat == 1) ? Wk : (mat == 2) ? Wv : Wo;
    u16* Wt = wt + (size_t)mat * (DM * DM);
    int bx = blockIdx.x * 32, by = blockIdx.y * 32;
    int tx = threadIdx.x & 31, ty = threadIdx.x >> 5;  // ty in [0,8)
#pragma unroll
    for (int k = 0; k < 4; k++)
        tile[ty + k * 8][tx] = W[(by + ty + k * 8) * DM + bx + tx];
    __syncthreads();
#pragma unroll
    for (int k = 0; k < 4; k++)
        Wt[(bx + ty + k * 8) * DM + by + tx] = f2bf(tile[tx][ty + k * 8]);
}

// ---------- cast q,k,v fp32 -> bf16 ----------
__global__ __launch_bounds__(256) void xcast_kernel(
    const float* __restrict__ q, const float* __restrict__ k,
    const float* __restrict__ v, u16* __restrict__ x)
{
    int seg = blockIdx.y;
    const float* src = (seg == 0) ? q : (seg == 1) ? k : v;
    u16* dst = x + (size_t)seg * (MM * DM);
    int i = blockIdx.x * 256 + threadIdx.x;  // float4 group index
    float4 f = ((const float4*)src)[i];
    u32 lo = (u32)f2bf(f.x) | ((u32)f2bf(f.y) << 16);
    u32 hi = (u32)f2bf(f.z) | ((u32)f2bf(f.w) << 16);
    ((uint2*)dst)[i] = make_uint2(lo, hi);
}

// ---------- QKV projection GEMM: 128x128 tile, 4 waves, 4x4 frags/wave ----------
__global__ __launch_bounds__(256) void proj_kernel(
    const u16* __restrict__ X, const u16* __restrict__ WT,
    const float* __restrict__ bq, const float* __restrict__ bk,
    const float* __restrict__ bv,
    u16* __restrict__ qh, u16* __restrict__ kh, u16* __restrict__ vh)
{
    int mode = blockIdx.z;
    const u16* A  = X  + (size_t)mode * (MM * DM);
    const u16* Bt = WT + (size_t)mode * (DM * DM);
    const float* bias = (mode == 0) ? bq : (mode == 1) ? bk : bv;
    u16* out = (mode == 0) ? qh : (mode == 1) ? kh : vh;

    __shared__ u16 As[128][40];
    __shared__ u16 Bs[128][40];

    int m0 = blockIdx.y * 128, n0 = blockIdx.x * 128;
    int t = threadIdx.x, wave = t >> 6, lane = t & 63;
    int quad = lane >> 4, c = lane & 15;
    int wm = wave >> 1, wn = wave & 1;           // 2x2 wave grid, 64x64 each
    int sr = t >> 2, sc4 = (t & 3) * 8;          // staging: row, col (elements)

    floatx4 acc[4][4];
#pragma unroll
    for (int i = 0; i < 4; i++)
#pragma unroll
        for (int j = 0; j < 4; j++)
            acc[i][j] = (floatx4){0.f, 0.f, 0.f, 0.f};

    for (int k0 = 0; k0 < DM; k0 += 32) {
        *(uint4*)&As[sr][sc4]      = *(const uint4*)&A [(size_t)(m0 + sr) * DM + k0 + sc4];
        *(uint4*)&As[sr + 64][sc4] = *(const uint4*)&A [(size_t)(m0 + sr + 64) * DM + k0 + sc4];
        *(uint4*)&Bs[sr][sc4]      = *(const uint4*)&Bt[(size_t)(n0 + sr) * DM + k0 + sc4];
        *(uint4*)&Bs[sr + 64][sc4] = *(const uint4*)&Bt[(size_t)(n0 + sr + 64) * DM + k0 + sc4];
        __syncthreads();
        short8 af[4], bf[4];
#pragma unroll
        for (int mi = 0; mi < 4; mi++)
            af[mi] = *(short8*)&As[wm * 64 + mi * 16 + c][quad * 8];
#pragma unroll
        for (int ni = 0; ni < 4; ni++)
            bf[ni] = *(short8*)&Bs[wn * 64 + ni * 16 + c][quad * 8];
#pragma unroll
        for (int mi = 0; mi < 4; mi++)
#pragma unroll
            for (int ni = 0; ni < 4; ni++)
                acc[mi][ni] = __builtin_amdgcn_mfma_f32_16x16x32_bf16(
                    af[mi], bf[ni], acc[mi][ni], 0, 0, 0);
        __syncthreads();
    }

#pragma unroll
    for (int mi = 0; mi < 4; mi++)
#pragma unroll
        for (int ni = 0; ni < 4; ni++) {
            int col = n0 + wn * 64 + ni * 16 + c;
            float bs = bias[col];
            int h = col >> 6, dk = col & 63;
#pragma unroll
            for (int r = 0; r < 4; r++) {
                int row = m0 + wm * 64 + mi * 16 + quad * 4 + r;
                float v = acc[mi][ni][r] + bs;
                if (mode == 0) v *= 0.125f;  // 1/sqrt(64)
                int b = row >> 11, s = row & 2047;
                out[(((size_t)(b * NH + h)) * SS + s) * DK + dk] = f2bf(v);
            }
        }
}

// ---------- transpose V: [B,H,S,DK] -> [B,H,DK,S] ----------
__global__ __launch_bounds__(256) void vtrans_kernel(
    const u16* __restrict__ vh, u16* __restrict__ vt)
{
    __shared__ u16 tile[32][33];
    int bh = blockIdx.z;
    const u16* src = vh + (size_t)bh * SS * DK;
    u16* dst = vt + (size_t)bh * DK * SS;
    int bx = blockIdx.x * 32;  // dk
    int by = blockIdx.y * 32;  // s
    int tx = threadIdx.x & 31, ty = threadIdx.x >> 5;
#pragma unroll
    for (int k = 0; k < 4; k++)
        tile[ty + k * 8][tx] = src[(size_t)(by + ty + k * 8) * DK + bx + tx];
    __syncthreads();
#pragma unroll
    for (int k = 0; k < 4; k++)
        dst[(size_t)(bx + ty + k * 8) * SS + by + tx] = tile[tx][ty + k * 8];
}

// ---------- attention v2: phase1 = QK+stats, phase2 = QK + weights + PV ----------
// block: 4 waves x 32 q-rows = 128 q-rows; KVBLK = 64; grid (16, 32)
__global__ __launch_bounds__(256) void attn_kernel(
    const u16* __restrict__ qh, const u16* __restrict__ kh,
    const u16* __restrict__ vt, u16* __restrict__ ctx,
    float* __restrict__ attw)
{
    int bh = blockIdx.y;
    int q0 = blockIdx.x * 128;
    const u16* Q  = qh + (size_t)bh * SS * DK;
    const u16* K  = kh + (size_t)bh * SS * DK;
    const u16* Vt = vt + (size_t)bh * DK * SS;

    int t = threadIdx.x, w = t >> 6, lane = t & 63;
    int quad = lane >> 4, c = lane & 15;

    __shared__ u16 Ks[64][72];       // K tile [kv][d], pad->2-way (free)
    __shared__ u16 Vs[64][72];       // V^T tile [dk][kv]
    __shared__ u16 Ps[4][32][72];    // per-wave P roundtrip (C-layout -> A-layout)

    // staging: 512 16B-chunks over a [64][64] bf16 tile, 2 per thread
    int sr0 = t >> 3, sco = (t & 7) * 8;
    int sr1 = sr0 + 32;

    // Q fragments: 32 rows per wave, held in registers all kernel
    short8 aq[2][2];
#pragma unroll
    for (int m = 0; m < 2; m++) {
        const u16* qr = Q + (size_t)(q0 + w * 32 + m * 16 + c) * DK;
        aq[m][0] = *(const short8*)(qr + quad * 8);
        aq[m][1] = *(const short8*)(qr + 32 + quad * 8);
    }

    float m_r[2][4], l_r[2][4];
#pragma unroll
    for (int m = 0; m < 2; m++)
#pragma unroll
        for (int r = 0; r < 4; r++) { m_r[m][r] = -1e30f; l_r[m][r] = 0.f; }

    // ---- phase 1: row max & sum only (no PV, no V traffic) ----
    for (int kt = 0; kt < SS; kt += 64) {
        *(uint4*)&Ks[sr0][sco] = *(const uint4*)&K[(size_t)(kt + sr0) * DK + sco];
        *(uint4*)&Ks[sr1][sco] = *(const uint4*)&K[(size_t)(kt + sr1) * DK + sco];
        __syncthreads();

        floatx4 sacc[2][4];
#pragma unroll
        for (int m = 0; m < 2; m++)
#pragma unroll
            for (int nt = 0; nt < 4; nt++)
                sacc[m][nt] = (floatx4){0.f, 0.f, 0.f, 0.f};
#pragma unroll
        for (int nt = 0; nt < 4; nt++) {
            short8 b0 = *(short8*)&Ks[nt * 16 + c][quad * 8];
            short8 b1 = *(short8*)&Ks[nt * 16 + c][32 + quad * 8];
#pragma unroll
            for (int m = 0; m < 2; m++) {
                sacc[m][nt] = __builtin_amdgcn_mfma_f32_16x16x32_bf16(aq[m][0], b0, sacc[m][nt], 0, 0, 0);
                sacc[m][nt] = __builtin_amdgcn_mfma_f32_16x16x32_bf16(aq[m][1], b1, sacc[m][nt], 0, 0, 0);
            }
        }

#pragma unroll
        for (int m = 0; m < 2; m++)
#pragma unroll
            for (int r = 0; r < 4; r++) {
                float mx = fmaxf(fmaxf(sacc[m][0][r], sacc[m][1][r]),
                                 fmaxf(sacc[m][2][r], sacc[m][3][r]));
#pragma unroll
                for (int off = 8; off; off >>= 1)
                    mx = fmaxf(mx, __shfl_xor(mx, off));
                float mo = m_r[m][r];
                float mn = fmaxf(mo, mx);
                float rs = __expf(sacc[m][0][r] - mn) + __expf(sacc[m][1][r] - mn)
                         + __expf(sacc[m][2][r] - mn) + __expf(sacc[m][3][r] - mn);
#pragma unroll
                for (int off = 8; off; off >>= 1)
                    rs += __shfl_xor(rs, off);
                m_r[m][r] = mn;
                l_r[m][r] = l_r[m][r] * __expf(mo - mn) + rs;
            }
        __syncthreads();
    }

    float rl[2][4];
#pragma unroll
    for (int m = 0; m < 2; m++)
#pragma unroll
        for (int r = 0; r < 4; r++) rl[m][r] = 1.0f / l_r[m][r];

    floatx4 cacc[2][4];
#pragma unroll
    for (int m = 0; m < 2; m++)
#pragma unroll
        for (int dt = 0; dt < 4; dt++) cacc[m][dt] = (floatx4){0.f, 0.f, 0.f, 0.f};

    float* awb = attw + (size_t)bh * ((size_t)SS * SS);

    // ---- phase 2: recompute scores, write normalized weights, PV (no rescale) ----
    for (int kt = 0; kt < SS; kt += 64) {
        *(uint4*)&Ks[sr0][sco] = *(const uint4*)&K[(size_t)(kt + sr0) * DK + sco];
        *(uint4*)&Ks[sr1][sco] = *(const uint4*)&K[(size_t)(kt + sr1) * DK + sco];
        *(uint4*)&Vs[sr0][sco] = *(const uint4*)&Vt[(size_t)sr0 * SS + kt + sco];
        *(uint4*)&Vs[sr1][sco] = *(const uint4*)&Vt[(size_t)sr1 * SS + kt + sco];
        __syncthreads();

        floatx4 sacc[2][4];
#pragma unroll
        for (int m = 0; m < 2; m++)
#pragma unroll
            for (int nt = 0; nt < 4; nt++)
                sacc[m][nt] = (floatx4){0.f, 0.f, 0.f, 0.f};
#pragma unroll
        for (int nt = 0; nt < 4; nt++) {
            short8 b0 = *(short8*)&Ks[nt * 16 + c][quad * 8];
            short8 b1 = *(short8*)&Ks[nt * 16 + c][32 + quad * 8];
#pragma unroll
            for (int m = 0; m < 2; m++) {
                sacc[m][nt] = __builtin_amdgcn_mfma_f32_16x16x32_bf16(aq[m][0], b0, sacc[m][nt], 0, 0, 0);
                sacc[m][nt] = __builtin_amdgcn_mfma_f32_16x16x32_bf16(aq[m][1], b1, sacc[m][nt], 0, 0, 0);
            }
        }

        // normalized weights: nontemporal fp32 stream + bf16 into LDS for PV
#pragma unroll
        for (int m = 0; m < 2; m++)
#pragma unroll
            for (int r = 0; r < 4; r++) {
                size_t ro = (size_t)(q0 + w * 32 + m * 16 + quad * 4 + r) * SS + kt;
                float mm = m_r[m][r], rr = rl[m][r];
#pragma unroll
                for (int nt = 0; nt < 4; nt++) {
                    float wgt = __expf(sacc[m][nt][r] - mm) * rr;
                    __builtin_nontemporal_store(wgt, &awb[ro + nt * 16 + c]);
                    Ps[w][m * 16 + quad * 4 + r][nt * 16 + c] = f2bf(wgt);
                }
            }

        // PV: ctx += P @ V  (weights already normalized -> plain accumulate)
        short8 bv[4][2];
#pragma unroll
        for (int dt = 0; dt < 4; dt++) {
            bv[dt][0] = *(short8*)&Vs[dt * 16 + c][quad * 8];
            bv[dt][1] = *(short8*)&Vs[dt * 16 + c][32 + quad * 8];
        }
#pragma unroll
        for (int m = 0; m < 2; m++) {
            short8 ap0 = *(short8*)&Ps[w][m * 16 + c][quad * 8];
            short8 ap1 = *(short8*)&Ps[w][m * 16 + c][32 + quad * 8];
#pragma unroll
            for (int dt = 0; dt < 4; dt++) {
                cacc[m][dt] = __builtin_amdgcn_mfma_f32_16x16x32_bf16(ap0, bv[dt][0], cacc[m][dt], 0, 0, 0);
                cacc[m][dt] = __builtin_amdgcn_mfma_f32_16x16x32_bf16(ap1, bv[dt][1], cacc[m][dt], 0, 0, 0);
            }
        }
        __syncthreads();
    }

    // ctx epilogue (already normalized, no division)
    int b = bh >> 4, h = bh & 15;
#pragma unroll
    for (int m = 0; m < 2; m++)
#pragma unroll
        for (int r = 0; r < 4; r++) {
            size_t orow = (size_t)(b * SS + q0 + w * 32 + m * 16 + quad * 4 + r) * DM + h * DK;
#pragma unroll
            for (int dt = 0; dt < 4; dt++)
                ctx[orow + dt * 16 + c] = f2bf(cacc[m][dt][r]);
        }
}

// ---------- output projection: 128x64 tile, 4 waves (2x2), fp32 out ----------
__global__ __launch_bounds__(256) void outproj_kernel(
    const u16* __restrict__ A, const u16* __restrict__ Bt,
    const float* __restrict__ bias, float* __restrict__ out)
{
    __shared__ u16 As[128][40];
    __shared__ u16 Bs[64][40];
    int m0 = blockIdx.y * 128, n0 = blockIdx.x * 64;
    int t = threadIdx.x, wave = t >> 6, lane = t & 63;
    int quad = lane >> 4, c = lane & 15;
    int wm = wave >> 1, wn = wave & 1;   // wave covers 64x32
    int sr = t >> 2, sc4 = (t & 3) * 8;

    floatx4 acc[4][2];
#pragma unroll
    for (int i = 0; i < 4; i++)
#pragma unroll
        for (int j = 0; j < 2; j++)
            acc[i][j] = (floatx4){0.f, 0.f, 0.f, 0.f};

    for (int k0 = 0; k0 < DM; k0 += 32) {
        *(uint4*)&As[sr][sc4]      = *(const uint4*)&A [(size_t)(m0 + sr) * DM + k0 + sc4];
        *(uint4*)&As[sr + 64][sc4] = *(const uint4*)&A [(size_t)(m0 + sr + 64) * DM + k0 + sc4];
        *(uint4*)&Bs[sr][sc4]      = *(const uint4*)&Bt[(size_t)(n0 + sr) * DM + k0 + sc4];
        __syncthreads();
        short8 af[4], bf[2];
#pragma unroll
        for (int mi = 0; mi < 4; mi++)
            af[mi] = *(short8*)&As[wm * 64 + mi * 16 + c][quad * 8];
#pragma unroll
        for (int ni = 0; ni < 2; ni++)
            bf[ni] = *(short8*)&Bs[wn * 32 + ni * 16 + c][quad * 8];
#pragma unroll
        for (int mi = 0; mi < 4; mi++)
#pragma unroll
            for (int ni = 0; ni < 2; ni++)
                acc[mi][ni] = __builtin_amdgcn_mfma_f32_16x16x32_bf16(
                    af[mi], bf[ni], acc[mi][ni], 0, 0, 0);
        __syncthreads();
    }

#pragma unroll
    for (int mi = 0; mi < 4; mi++)
#pragma unroll
        for (int ni = 0; ni < 2; ni++) {
            int col = n0 + wn * 32 + ni * 16 + c;
            float bs = bias[col];
#pragma unroll
            for (int r = 0; r < 4; r++) {
                int row = m0 + wm * 64 + mi * 16 + quad * 4 + r;
                out[(size_t)row * DM + col] = acc[mi][ni][r] + bs;
            }
        }
}

extern "C" void kernel_launch(void* const* d_in, const int* in_sizes, int n_in,
                              void* d_out, int out_size, void* d_ws, size_t ws_size,
                              hipStream_t stream)
{
    const float* q  = (const float*)d_in[0];
    const float* k  = (const float*)d_in[1];
    const float* v  = (const float*)d_in[2];
    const float* Wq = (const float*)d_in[3];
    const float* bq = (const float*)d_in[4];
    const float* Wk = (const float*)d_in[5];
    const float* bk = (const float*)d_in[6];
    const float* Wv = (const float*)d_in[7];
    const float* bv = (const float*)d_in[8];
    const float* Wo = (const float*)d_in[9];
    const float* bo = (const float*)d_in[10];
    float* out = (float*)d_out;
    char* ws = (char*)d_ws;

    u16* xq  = (u16*)(ws + WS_X);
    u16* wt  = (u16*)(ws + WS_WT);
    u16* qh  = (u16*)(ws + WS_QH);
    u16* kh  = (u16*)(ws + WS_KH);
    u16* vh  = (u16*)(ws + WS_VH);
    u16* vt  = (u16*)(ws + WS_VT);
    u16* ctx = (u16*)(ws + WS_CTX);

    wcast_kernel<<<dim3(32, 32, 4), 256, 0, stream>>>(Wq, Wk, Wv, Wo, wt);
    xcast_kernel<<<dim3(4096, 3), 256, 0, stream>>>(q, k, v, xq);
    proj_kernel<<<dim3(8, 32, 3), 256, 0, stream>>>(xq, wt, bq, bk, bv, qh, kh, vh);
    vtrans_kernel<<<dim3(2, 64, 32), 256, 0, stream>>>(vh, vt);
    attn_kernel<<<dim3(16, 32), 256, 0, stream>>>(qh, kh, vt, ctx, out + 4194304);
    outproj_kernel<<<dim3(16, 32), 256, 0, stream>>>(ctx, wt + 3 * (DM * DM), bo, out);
}